// Round 7
// baseline (215.500 us; speedup 1.0000x reference)
//
#include <hip/hip_runtime.h>
#include <hip/hip_bf16.h>
#include <cstddef>
#include <cstdint>

// Problem dims
constexpr int Nn = 4096;
constexpr int Ss = 128;
constexpr int Ff = 128;
constexpr int Dd = 256;
constexpr float EPSV = 1e-8f;

// d_out layout (floats): h_o [N*D], C_new [N*S*F], k [N*F], r [N*F]
constexpr size_t HO_OFF = 0;
constexpr size_t C_OFF  = (size_t)Nn * Dd;
constexpr size_t K_OFF  = C_OFF + (size_t)Nn * Ss * Ff;
constexpr size_t R_OFF  = K_OFF + (size_t)Nn * Ff;

typedef __attribute__((ext_vector_type(4))) float f4v;
typedef __attribute__((ext_vector_type(8))) short bh8;
typedef __attribute__((ext_vector_type(4))) short bh4;

// bf16 weight pack offsets in ws (units: shorts)
constexpr int WK_O  = 0;        // Wk   128x256
constexpr int WHH_O = 32768;    // Whh  768x256
constexpr int WIH_O = 229376;   // Wih  768x128
constexpr int WEV_O = 327680;   // [We;Wv] 256x256
constexpr int W_TOT = 393216;

__device__ __forceinline__ float sigmf(float x) { return 1.0f / (1.0f + __expf(-x)); }

__device__ __forceinline__ short f2bf(float x) {
    __hip_bfloat16 h = __float2bfloat16(x);   // RNE
    return *reinterpret_cast<short*>(&h);
}

// XOR swizzle: spread 16B k-slots of row r across banks. Row strides 512B / 256B.
__device__ __forceinline__ int swzH(int row, int kb) { return row * 512 + (kb ^ ((row & 7) << 4)); }
__device__ __forceinline__ int swzR(int row, int kb) { return row * 256 + (kb ^ ((row & 7) << 4)); }

__device__ __forceinline__ f4v mfma16(bh8 a, bh8 b, f4v c) {
    return __builtin_amdgcn_mfma_f32_16x16x32_bf16(a, b, c, 0, 0, 0);
}

// ---------------------------------------------------------------------------
// Prep: convert all weights to bf16, packed row-major into ws.
// ---------------------------------------------------------------------------
__global__ __launch_bounds__(256) void prep_weights(
    const float* __restrict__ Wk, const float* __restrict__ Whh,
    const float* __restrict__ Wih, const float* __restrict__ We,
    const float* __restrict__ Wv, short* __restrict__ out)
{
    int id = blockIdx.x * 256 + threadIdx.x;   // grid covers W_TOT exactly
    float v;
    if      (id < WHH_O) v = Wk[id - WK_O];
    else if (id < WIH_O) v = Whh[id - WHH_O];
    else if (id < WEV_O) v = Wih[id - WIH_O];
    else if (id < WEV_O + 32768) v = We[id - WEV_O];
    else v = Wv[id - WEV_O - 32768];
    out[id] = f2bf(v);
}

// ---------------------------------------------------------------------------
// Mega kernel: 512 blocks x 512 threads; block handles 8 rows, wave w = row w
// for per-row phases. launch_bounds(512,2): VGPR cap >=128 so the 8-deep load
// pipelines live in registers (R6's (512,4) capped at 64 -> scratch spills).
//  P0 load h (fp32 + swizzled bf16, zero pads)
//  P1 k = h@Wk^T + bk                       [MFMA, all waves]
//  P2 per-row: knorm, beta, ONE pass over C: p=exp(x-beta) (fixed shift),
//     rolling 8-deep load pipeline
//  P3 gh+gi fused gates pre-activations     [MFMA, all waves]
//  P4 per-row gates -> h_o
//  P5 [e|v] = sig/lin(h_o@[We;Wv]^T)        [MFMA, all waves]
//  P6 per-row: C_new = C*(1-w*e)+w*v, rolling 8-deep, L3-hot reads, NT store
// ---------------------------------------------------------------------------
__global__ __launch_bounds__(512, 2) void mega_kernel(
    const float* __restrict__ C, const float* __restrict__ h_prev,
    const short* __restrict__ WB,
    const float* __restrict__ Wb, const float* __restrict__ bb,
    const float* __restrict__ bk, const float* __restrict__ bhh,
    const float* __restrict__ bih, const float* __restrict__ be,
    const float* __restrict__ bv,
    float* __restrict__ ho, float* __restrict__ Cnew,
    float* __restrict__ kout, float* __restrict__ rout)
{
    __shared__ float sH[8][256];                  // h_prev fp32
    __shared__ __align__(16) short sHb[16 * 256]; // h (later h_o) bf16, 16-row pad, swizzled
    __shared__ __align__(16) short sRb[16 * 128]; // r bf16, 16-row pad, swizzled
    __shared__ float sK[8][128];
    __shared__ float sSc[8][128];                 // p = exp(x - beta) per (row, s)
    __shared__ float sGs[8][768];                 // [0,512): gi+gh summed; [512,768): h_n only
    __shared__ float sGn[8][256];                 // i_n
    __shared__ float sEV[8][256];                 // e | v

    const int t  = threadIdx.x;
    const int l  = t & 63;
    const int wv = t >> 6;
    const int nb = blockIdx.x * 8;
    char* hb = (char*)sHb;
    char* rb = (char*)sRb;

    const short* WkB  = WB + WK_O;
    const short* WhhB = WB + WHH_O;
    const short* WihB = WB + WIH_O;
    const short* WevB = WB + WEV_O;

    // ---- P0: load h rows, build bf16 copies, zero pad rows (bounds-correct)
    {
        const int f = t * 4, row = f >> 8, col = f & 255;
        float4 hv = *(const float4*)(h_prev + (size_t)(nb + row) * Dd + col);
        *(float4*)&sH[row][col] = hv;
        bh4 hb4 = { f2bf(hv.x), f2bf(hv.y), f2bf(hv.z), f2bf(hv.w) };
        *(bh4*)(hb + swzH(row, col * 2)) = hb4;
        *(int64_t*)(hb + 4096 + t * 8) = 0;   // sHb rows 8..15 (bytes 4096..8191)
        *(int*)(rb + 2048 + t * 4) = 0;       // sRb rows 8..15 (bytes 2048..4095)
    }
    __syncthreads();

    // ---- P1: k = h @ Wk^T + bk (each wave: one 16-col tile, all rows)
    {
        const int fr = l & 15, kq = l >> 4, rbase = kq * 4;
        const int colg = wv * 16 + fr;
        f4v acc = {0.f, 0.f, 0.f, 0.f};
#pragma unroll
        for (int kc = 0; kc < 8; ++kc) {
            bh8 a = *(const bh8*)(hb + swzH(fr, kc * 64 + kq * 16));
            bh8 b = *(const bh8*)(WkB + (size_t)colg * 256 + kc * 32 + kq * 8);
            acc = mfma16(a, b, acc);
        }
        if (rbase < 8) {
            const float bs = bk[colg];
#pragma unroll
            for (int rg = 0; rg < 4; ++rg) {
                float x = acc[rg] + bs;
                sK[rbase + rg][colg] = x;
                kout[(size_t)(nb + rbase + rg) * Ff + colg] = x;
            }
        }
    }
    __syncthreads();

    // ---- P2: per-row attention, single pass, fixed-shift softmax (M = beta)
    float invL_r = 0.0f;   // live to P6
    {
        const int half = l >> 5, fl = l & 31, f4 = fl * 4;
        const float* Cn = C + (size_t)(nb + wv) * (Ss * Ff);

        float kv0 = sK[wv][l], kv1 = sK[wv][64 + l];
        float ks = kv0 * kv0 + kv1 * kv1;
#pragma unroll
        for (int o = 32; o > 0; o >>= 1) ks += __shfl_xor(ks, o);
        const float knorm = fmaxf(sqrtf(ks), EPSV);

        float4 hv = *(const float4*)&sH[wv][l * 4];
        float4 wb4 = *(const float4*)(Wb + l * 4);
        float bp = hv.x * wb4.x + hv.y * wb4.y + hv.z * wb4.z + hv.w * wb4.w;
#pragma unroll
        for (int o = 32; o > 0; o >>= 1) bp += __shfl_xor(bp, o);
        bp += bb[0];
        const float beta = ((bp > 20.0f) ? bp : log1pf(__expf(bp))) + 1.0f;

        const float4 kreg = *(const float4*)&sK[wv][f4];
        float lsum = 0.0f;
        f4v racc = {0.f, 0.f, 0.f, 0.f};

        // rolling 8-deep pipeline: consume buf[j], immediately reload buf[j]
        f4v buf[8];
#pragma unroll
        for (int j = 0; j < 8; ++j)
            buf[j] = *(const f4v*)(Cn + (size_t)(j * 2 + half) * Ff + f4);
#pragma unroll 1
        for (int g = 0; g < 8; ++g) {
#pragma unroll
            for (int j = 0; j < 8; ++j) {
                const int s = g * 16 + j * 2 + half;
                const f4v c4 = buf[j];
                if (g < 7)
                    buf[j] = *(const f4v*)(Cn + (size_t)(s + 16) * Ff + f4);
                float d = c4.x * kreg.x + c4.y * kreg.y + c4.z * kreg.z + c4.w * kreg.w;
                float q = c4.x * c4.x + c4.y * c4.y + c4.z * c4.z + c4.w * c4.w;
#pragma unroll
                for (int o = 16; o > 0; o >>= 1) {
                    d += __shfl_xor(d, o);
                    q += __shfl_xor(q, o);
                }
                const float cn = fmaxf(sqrtf(q), EPSV);
                const float x = d / (cn * knorm) * beta;    // x <= beta always
                const float p = __expf(x - beta);
                if (fl == 0) sSc[wv][s] = p;
                lsum += p;
                racc += p * c4;
            }
        }
        // combine even/odd-s halves (same shift, plain add)
        const float L = lsum + __shfl_xor(lsum, 32);
        f4v r2;
        r2.x = __shfl_xor(racc.x, 32); r2.y = __shfl_xor(racc.y, 32);
        r2.z = __shfl_xor(racc.z, 32); r2.w = __shfl_xor(racc.w, 32);
        const float iL = 1.0f / L;
        f4v r4 = (racc + r2) * iL;
        if (half == 0) {
            *(f4v*)(rout + (size_t)(nb + wv) * Ff + f4) = r4;
            bh4 rb4 = { f2bf(r4.x), f2bf(r4.y), f2bf(r4.z), f2bf(r4.w) };
            *(bh4*)(rb + swzR(wv, f4 * 2)) = rb4;
        }
        invL_r = iL;
    }
    __syncthreads();

    // ---- P3: gh = h@Whh^T + bhh; gi = r@Wih^T + bih; store sums / n-parts
    {
        const int fr = l & 15, kq = l >> 4, rbase = kq * 4;
#pragma unroll
        for (int i = 0; i < 6; ++i) {
            const int colg = i * 128 + wv * 16 + fr;
            f4v aG = {0.f, 0.f, 0.f, 0.f}, aI = {0.f, 0.f, 0.f, 0.f};
#pragma unroll
            for (int kc = 0; kc < 8; ++kc) {
                bh8 a = *(const bh8*)(hb + swzH(fr, kc * 64 + kq * 16));
                bh8 b = *(const bh8*)(WhhB + (size_t)colg * 256 + kc * 32 + kq * 8);
                aG = mfma16(a, b, aG);
            }
#pragma unroll
            for (int kc = 0; kc < 4; ++kc) {
                bh8 a = *(const bh8*)(rb + swzR(fr, kc * 64 + kq * 16));
                bh8 b = *(const bh8*)(WihB + (size_t)colg * 128 + kc * 32 + kq * 8);
                aI = mfma16(a, b, aI);
            }
            if (rbase < 8) {
                if (colg < 512) {
                    const float bs = bhh[colg] + bih[colg];
#pragma unroll
                    for (int rg = 0; rg < 4; ++rg)
                        sGs[rbase + rg][colg] = aG[rg] + aI[rg] + bs;
                } else {   // n-gate: keep h_n and i_n separate
                    const float b1 = bhh[colg], b2 = bih[colg];
#pragma unroll
                    for (int rg = 0; rg < 4; ++rg) {
                        sGs[rbase + rg][colg]       = aG[rg] + b1;
                        sGn[rbase + rg][colg - 512] = aI[rg] + b2;
                    }
                }
            }
        }
    }
    __syncthreads();

    // ---- P4: gates -> h_o (wave w, row w; lane covers 4 d's)
    {
        const int d4 = l * 4;
        float4 gr  = *(const float4*)&sGs[wv][d4];
        float4 gz  = *(const float4*)&sGs[wv][256 + d4];
        float4 hn  = *(const float4*)&sGs[wv][512 + d4];
        float4 in_ = *(const float4*)&sGn[wv][d4];
        float4 hp  = *(const float4*)&sH[wv][d4];
        float4 o;
        { float rg = sigmf(gr.x), z = sigmf(gz.x);
          float nn = tanhf(in_.x + rg * hn.x); o.x = (1.0f - z) * nn + z * hp.x; }
        { float rg = sigmf(gr.y), z = sigmf(gz.y);
          float nn = tanhf(in_.y + rg * hn.y); o.y = (1.0f - z) * nn + z * hp.y; }
        { float rg = sigmf(gr.z), z = sigmf(gz.z);
          float nn = tanhf(in_.z + rg * hn.z); o.z = (1.0f - z) * nn + z * hp.z; }
        { float rg = sigmf(gr.w), z = sigmf(gz.w);
          float nn = tanhf(in_.w + rg * hn.w); o.w = (1.0f - z) * nn + z * hp.w; }
        *(float4*)(ho + (size_t)(nb + wv) * Dd + d4) = o;
        bh4 ob = { f2bf(o.x), f2bf(o.y), f2bf(o.z), f2bf(o.w) };
        *(bh4*)(hb + swzH(wv, d4 * 2)) = ob;    // sHb now holds h_o
    }
    __syncthreads();

    // ---- P5: [e|v] = h_o @ [We;Wv]^T (+sigmoid on e)
    {
        const int fr = l & 15, kq = l >> 4, rbase = kq * 4;
#pragma unroll
        for (int i = 0; i < 2; ++i) {
            const int colg = i * 128 + wv * 16 + fr;
            f4v acc = {0.f, 0.f, 0.f, 0.f};
#pragma unroll
            for (int kc = 0; kc < 8; ++kc) {
                bh8 a = *(const bh8*)(hb + swzH(fr, kc * 64 + kq * 16));
                bh8 b = *(const bh8*)(WevB + (size_t)colg * 256 + kc * 32 + kq * 8);
                acc = mfma16(a, b, acc);
            }
            if (rbase < 8) {
                const float bs = (colg < 128) ? be[colg] : bv[colg - 128];
#pragma unroll
                for (int rg = 0; rg < 4; ++rg) {
                    float x = acc[rg] + bs;
                    if (colg < 128) x = sigmf(x);
                    sEV[rbase + rg][colg] = x;
                }
            }
        }
    }
    __syncthreads();

    // ---- P6: C_new = C*(1 - w*e) + w*v, rolling 8-deep (L2/L3-hot), NT store
    {
        const int half = l >> 5, fl = l & 31, f4 = fl * 4;
        const float* Cn = C    + (size_t)(nb + wv) * (Ss * Ff);
        float*       Co = Cnew + (size_t)(nb + wv) * (Ss * Ff);
        const f4v e4 = *(const f4v*)&sEV[wv][f4];
        const f4v v4 = *(const f4v*)&sEV[wv][128 + f4];
        const float iL = invL_r;

        f4v buf[8];
#pragma unroll
        for (int j = 0; j < 8; ++j)
            buf[j] = *(const f4v*)(Cn + (size_t)(j * 2 + half) * Ff + f4);
#pragma unroll 1
        for (int g = 0; g < 8; ++g) {
#pragma unroll
            for (int j = 0; j < 8; ++j) {
                const int s = g * 16 + j * 2 + half;
                const f4v c4 = buf[j];
                if (g < 7)
                    buf[j] = *(const f4v*)(Cn + (size_t)(s + 16) * Ff + f4);
                const float wsc = sSc[wv][s] * iL;
                f4v o = c4 * (1.0f - wsc * e4) + wsc * v4;
                __builtin_nontemporal_store(o, (f4v*)(Co + (size_t)s * Ff + f4));
            }
        }
    }
}

// ---------------------------------------------------------------------------
extern "C" void kernel_launch(void* const* d_in, const int* in_sizes, int n_in,
                              void* d_out, int out_size, void* d_ws, size_t ws_size,
                              hipStream_t stream)
{
    const float* h_prev = (const float*)d_in[0];
    const float* C      = (const float*)d_in[1];
    const float* Wk     = (const float*)d_in[2];
    const float* bk     = (const float*)d_in[3];
    const float* Wb     = (const float*)d_in[4];
    const float* bb     = (const float*)d_in[5];
    const float* We     = (const float*)d_in[6];
    const float* be     = (const float*)d_in[7];
    const float* Wv     = (const float*)d_in[8];
    const float* bv     = (const float*)d_in[9];
    const float* Wih    = (const float*)d_in[10];
    const float* Whh    = (const float*)d_in[11];
    const float* bih    = (const float*)d_in[12];
    const float* bhh    = (const float*)d_in[13];

    float* out  = (float*)d_out;
    float* ho   = out + HO_OFF;
    float* Cnew = out + C_OFF;
    float* kbuf = out + K_OFF;
    float* rbuf = out + R_OFF;

    short* wsB = (short*)d_ws;

    prep_weights<<<W_TOT / 256, 256, 0, stream>>>(Wk, Whh, Wih, We, Wv, wsB);

    mega_kernel<<<Nn / 8, 512, 0, stream>>>(
        C, h_prev, wsB, Wb, bb, bk, bhh, bih, be, bv,
        ho, Cnew, kbuf, rbuf);
}

// Round 8
// 197.343 us; speedup vs baseline: 1.0920x; 1.0920x over previous
//
#include <hip/hip_runtime.h>
#include <hip/hip_bf16.h>
#include <cstddef>
#include <cstdint>

// Problem dims
constexpr int Nn = 4096;
constexpr int Ss = 128;
constexpr int Ff = 128;
constexpr int Dd = 256;
constexpr float EPSV = 1e-8f;

// d_out layout (floats): h_o [N*D], C_new [N*S*F], k [N*F], r [N*F]
constexpr size_t HO_OFF = 0;
constexpr size_t C_OFF  = (size_t)Nn * Dd;
constexpr size_t K_OFF  = C_OFF + (size_t)Nn * Ss * Ff;
constexpr size_t R_OFF  = K_OFF + (size_t)Nn * Ff;

typedef __attribute__((ext_vector_type(4))) float f4v;
typedef __attribute__((ext_vector_type(8))) short bh8;
typedef __attribute__((ext_vector_type(4))) short bh4;

// bf16 weight pack offsets in ws (units: shorts)
constexpr int WK_O  = 0;        // Wk   128x256
constexpr int WHH_O = 32768;    // Whh  768x256
constexpr int WIH_O = 229376;   // Wih  768x128
constexpr int WEV_O = 327680;   // [We;Wv] 256x256
constexpr int W_TOT = 393216;

#define WAITVM(N) asm volatile("s_waitcnt vmcnt(" #N ")" ::: "memory")

__device__ __forceinline__ float sigmf(float x) { return 1.0f / (1.0f + __expf(-x)); }

__device__ __forceinline__ short f2bf(float x) {
    __hip_bfloat16 h = __float2bfloat16(x);   // RNE
    return *reinterpret_cast<short*>(&h);
}

// async global->LDS DMA: 64 lanes x 16B -> ldsbase + lane*16 (1 KB per call)
__device__ __forceinline__ void gll16(const float* g, float* l) {
    __builtin_amdgcn_global_load_lds(
        (const __attribute__((address_space(1))) void*)g,
        (__attribute__((address_space(3))) void*)l,
        16, 0, 0);
}

// XOR swizzle: spread 16B k-slots of row r across banks. Row strides 512B / 256B.
__device__ __forceinline__ int swzH(int row, int kb) { return row * 512 + (kb ^ ((row & 7) << 4)); }
__device__ __forceinline__ int swzR(int row, int kb) { return row * 256 + (kb ^ ((row & 7) << 4)); }

__device__ __forceinline__ f4v mfma16(bh8 a, bh8 b, f4v c) {
    return __builtin_amdgcn_mfma_f32_16x16x32_bf16(a, b, c, 0, 0, 0);
}

// ---------------------------------------------------------------------------
// Prep: convert all weights to bf16, packed row-major into ws.
// ---------------------------------------------------------------------------
__global__ __launch_bounds__(256) void prep_weights(
    const float* __restrict__ Wk, const float* __restrict__ Whh,
    const float* __restrict__ Wih, const float* __restrict__ We,
    const float* __restrict__ Wv, short* __restrict__ out)
{
    int id = blockIdx.x * 256 + threadIdx.x;   // grid covers W_TOT exactly
    float v;
    if      (id < WHH_O) v = Wk[id - WK_O];
    else if (id < WIH_O) v = Whh[id - WHH_O];
    else if (id < WEV_O) v = Wih[id - WIH_O];
    else if (id < WEV_O + 32768) v = We[id - WEV_O];
    else v = Wv[id - WEV_O - 32768];
    out[id] = f2bf(v);
}

// ---------------------------------------------------------------------------
// Mega kernel: 512 blocks x 512 threads; block handles 8 rows, wave w = row w.
//  P0 load h (fp32 + swizzled bf16, zero pads)
//  P1 k = h@Wk^T + bk                          [MFMA]
//  P2 attention pass over C: DMA ring (4x1KB/wave, vmcnt(3)) -> LDS -> compute
//     fixed-shift softmax p=exp(x-beta); r accumulated online
//  P3 gh/gi MFMAs -> GRU gates IN REGISTERS -> h_o (sGs/sGn eliminated)
//  P5 [e|v] = sig/lin(h_o@[We;Wv]^T)           [MFMA]
//  P6 C_new = C*(1-w*e)+w*v: DMA batch-4 + vmcnt(0), L3-hot reads, NT store
// ---------------------------------------------------------------------------
__global__ __launch_bounds__(512, 2) void mega_kernel(
    const float* __restrict__ C, const float* __restrict__ h_prev,
    const short* __restrict__ WB,
    const float* __restrict__ Wb, const float* __restrict__ bb,
    const float* __restrict__ bk, const float* __restrict__ bhh,
    const float* __restrict__ bih, const float* __restrict__ be,
    const float* __restrict__ bv,
    float* __restrict__ ho, float* __restrict__ Cnew,
    float* __restrict__ kout, float* __restrict__ rout)
{
    __shared__ float sH[8][256];                  // h_prev fp32            8 KB
    __shared__ __align__(16) short sHb[16 * 256]; // h/h_o bf16 swizzled    8 KB
    __shared__ __align__(16) short sRb[16 * 128]; // r bf16 swizzled        4 KB
    __shared__ float sK[8][128];                  //                        4 KB
    __shared__ float sSc[8][128];                 // p per (row,s)          4 KB
    __shared__ float sEV[8][256];                 // e | v                  8 KB
    __shared__ __align__(16) float sStage[8][1024]; // DMA ring, 4KB/wave  32 KB

    const int t  = threadIdx.x;
    const int l  = t & 63;
    const int wv = t >> 6;
    const int nb = blockIdx.x * 8;
    char* hb = (char*)sHb;
    char* rb = (char*)sRb;

    const short* WkB  = WB + WK_O;
    const short* WhhB = WB + WHH_O;
    const short* WihB = WB + WIH_O;
    const short* WevB = WB + WEV_O;

    // ---- P0: load h rows, build bf16 copies, zero pad rows
    {
        const int f = t * 4, row = f >> 8, col = f & 255;
        float4 hv = *(const float4*)(h_prev + (size_t)(nb + row) * Dd + col);
        *(float4*)&sH[row][col] = hv;
        bh4 hb4 = { f2bf(hv.x), f2bf(hv.y), f2bf(hv.z), f2bf(hv.w) };
        *(bh4*)(hb + swzH(row, col * 2)) = hb4;
        *(int64_t*)(hb + 4096 + t * 8) = 0;   // sHb rows 8..15
        *(int*)(rb + 2048 + t * 4) = 0;       // sRb rows 8..15
    }
    __syncthreads();

    // ---- P1: k = h @ Wk^T + bk
    {
        const int fr = l & 15, kq = l >> 4, rbase = kq * 4;
        const int colg = wv * 16 + fr;
        f4v acc = {0.f, 0.f, 0.f, 0.f};
#pragma unroll
        for (int kc = 0; kc < 8; ++kc) {
            bh8 a = *(const bh8*)(hb + swzH(fr, kc * 64 + kq * 16));
            bh8 b = *(const bh8*)(WkB + (size_t)colg * 256 + kc * 32 + kq * 8);
            acc = mfma16(a, b, acc);
        }
        if (rbase < 8) {
            const float bs = bk[colg];
#pragma unroll
            for (int rg = 0; rg < 4; ++rg) {
                float x = acc[rg] + bs;
                sK[rbase + rg][colg] = x;
                kout[(size_t)(nb + rbase + rg) * Ff + colg] = x;
            }
        }
    }
    __syncthreads();

    // ---- P2: attention, DMA-ring staged single pass, fixed-shift softmax
    float invL_r = 0.0f;   // live to P6
    {
        const int half = l >> 5, fl = l & 31, f4 = fl * 4;
        const float* Cn = C + (size_t)(nb + wv) * (Ss * Ff);

        float kv0 = sK[wv][l], kv1 = sK[wv][64 + l];
        float ks = kv0 * kv0 + kv1 * kv1;
#pragma unroll
        for (int o = 32; o > 0; o >>= 1) ks += __shfl_xor(ks, o);
        const float knorm = fmaxf(sqrtf(ks), EPSV);

        float4 hv = *(const float4*)&sH[wv][l * 4];
        float4 wb4 = *(const float4*)(Wb + l * 4);
        float bp = hv.x * wb4.x + hv.y * wb4.y + hv.z * wb4.z + hv.w * wb4.w;
#pragma unroll
        for (int o = 32; o > 0; o >>= 1) bp += __shfl_xor(bp, o);
        bp += bb[0];
        const float beta = ((bp > 20.0f) ? bp : log1pf(__expf(bp))) + 1.0f;

        const float4 kreg = *(const float4*)&sK[wv][f4];
        float lsum = 0.0f;
        f4v racc = {0.f, 0.f, 0.f, 0.f};
        float* stg = &sStage[wv][0];

        WAITVM(0);   // drain kout stores etc -> ring owns vmcnt
#pragma unroll
        for (int k = 0; k < 4; ++k)
            gll16(Cn + k * 256 + l * 4, stg + k * 256);

#pragma unroll 4
        for (int k = 0; k < 64; ++k) {
            WAITVM(3);                       // slot k landed (3 younger in flight)
            const f4v c4 = *(const f4v*)(stg + (k & 3) * 256 + l * 4);
            // consume c4 (forces ds_read completion) before reusing the slot
            float d = c4.x * kreg.x + c4.y * kreg.y + c4.z * kreg.z + c4.w * kreg.w;
            float q = c4.x * c4.x + c4.y * c4.y + c4.z * c4.z + c4.w * c4.w;
            if (k < 60)
                gll16(Cn + (k + 4) * 256 + l * 4, stg + (k & 3) * 256);
#pragma unroll
            for (int o = 16; o > 0; o >>= 1) {
                d += __shfl_xor(d, o);
                q += __shfl_xor(q, o);
            }
            const int s = k * 2 + half;
            const float cn = fmaxf(sqrtf(q), EPSV);
            const float x = d / (cn * knorm) * beta;    // x <= beta always
            const float p = __expf(x - beta);
            if (fl == 0) sSc[wv][s] = p;
            lsum += p;
            racc += p * c4;
        }
        const float L = lsum + __shfl_xor(lsum, 32);
        f4v r2;
        r2.x = __shfl_xor(racc.x, 32); r2.y = __shfl_xor(racc.y, 32);
        r2.z = __shfl_xor(racc.z, 32); r2.w = __shfl_xor(racc.w, 32);
        const float iL = 1.0f / L;
        f4v r4 = (racc + r2) * iL;
        if (half == 0) {
            *(f4v*)(rout + (size_t)(nb + wv) * Ff + f4) = r4;
            bh4 rb4 = { f2bf(r4.x), f2bf(r4.y), f2bf(r4.z), f2bf(r4.w) };
            *(bh4*)(rb + swzR(wv, f4 * 2)) = rb4;
        }
        invL_r = iL;
    }
    __syncthreads();

    // ---- P3: gh/gi MFMAs; GRU gates in registers (wave wv owns d-slices
    //          {wv*16..+15} and {128+wv*16..+15} across all three gates)
    {
        const int fr = l & 15, kq = l >> 4, rbase = kq * 4;
        f4v aG[6], aI[6];
#pragma unroll
        for (int i = 0; i < 6; ++i) {
            const int colg = i * 128 + wv * 16 + fr;
            f4v g = {0.f, 0.f, 0.f, 0.f}, ii = {0.f, 0.f, 0.f, 0.f};
#pragma unroll
            for (int kc = 0; kc < 8; ++kc) {
                bh8 a = *(const bh8*)(hb + swzH(fr, kc * 64 + kq * 16));
                bh8 b = *(const bh8*)(WhhB + (size_t)colg * 256 + kc * 32 + kq * 8);
                g = mfma16(a, b, g);
            }
#pragma unroll
            for (int kc = 0; kc < 4; ++kc) {
                bh8 a = *(const bh8*)(rb + swzR(fr, kc * 64 + kq * 16));
                bh8 b = *(const bh8*)(WihB + (size_t)colg * 128 + kc * 32 + kq * 8);
                ii = mfma16(a, b, ii);
            }
            aG[i] = g; aI[i] = ii;
        }

        float hoReg[2][4];
        if (rbase < 8) {
#pragma unroll
            for (int dp = 0; dp < 2; ++dp) {
                const int d = dp * 128 + wv * 16 + fr;
                const float br  = bhh[d] + bih[d];
                const float bz  = bhh[256 + d] + bih[256 + d];
                const float bhn = bhh[512 + d];
                const float bin = bih[512 + d];
#pragma unroll
                for (int rg = 0; rg < 4; ++rg) {
                    const float rgt = sigmf(aG[dp][rg] + aI[dp][rg] + br);
                    const float z   = sigmf(aG[2 + dp][rg] + aI[2 + dp][rg] + bz);
                    const float nn  = tanhf(aI[4 + dp][rg] + bin + rgt * (aG[4 + dp][rg] + bhn));
                    const float hp  = sH[rbase + rg][d];
                    hoReg[dp][rg] = (1.0f - z) * nn + z * hp;
                }
            }
        }
        __syncthreads();   // all waves done reading sHb(h) as A-frags
        if (rbase < 8) {
#pragma unroll
            for (int dp = 0; dp < 2; ++dp) {
                const int d = dp * 128 + wv * 16 + fr;
#pragma unroll
                for (int rg = 0; rg < 4; ++rg) {
                    const int row = rbase + rg;
                    const float o = hoReg[dp][rg];
                    ho[(size_t)(nb + row) * Dd + d] = o;
                    *(short*)(hb + row * 512 + ((d * 2) ^ ((row & 7) << 4))) = f2bf(o);
                }
            }
        }
    }
    __syncthreads();

    // ---- P5: [e|v] = h_o @ [We;Wv]^T (+sigmoid on e)
    {
        const int fr = l & 15, kq = l >> 4, rbase = kq * 4;
#pragma unroll
        for (int i = 0; i < 2; ++i) {
            const int colg = i * 128 + wv * 16 + fr;
            f4v acc = {0.f, 0.f, 0.f, 0.f};
#pragma unroll
            for (int kc = 0; kc < 8; ++kc) {
                bh8 a = *(const bh8*)(hb + swzH(fr, kc * 64 + kq * 16));
                bh8 b = *(const bh8*)(WevB + (size_t)colg * 256 + kc * 32 + kq * 8);
                acc = mfma16(a, b, acc);
            }
            if (rbase < 8) {
                const float bs = (colg < 128) ? be[colg] : bv[colg - 128];
#pragma unroll
                for (int rg = 0; rg < 4; ++rg) {
                    float x = acc[rg] + bs;
                    if (colg < 128) x = sigmf(x);
                    sEV[rbase + rg][colg] = x;
                }
            }
        }
    }
    __syncthreads();

    // ---- P6: C_new = C*(1-w*e)+w*v; DMA batch-4 + vmcnt(0) (no load/store
    //          ordering assumptions), L2/L3-hot reads, NT stores
    {
        const int half = l >> 5, fl = l & 31, f4 = fl * 4;
        const float* Cn = C    + (size_t)(nb + wv) * (Ss * Ff);
        float*       Co = Cnew + (size_t)(nb + wv) * (Ss * Ff);
        const f4v e4 = *(const f4v*)&sEV[wv][f4];
        const f4v v4 = *(const f4v*)&sEV[wv][128 + f4];
        const float iL = invL_r;
        float* stg = &sStage[wv][0];

        WAITVM(0);   // drain ho stores / P2 leftovers before reusing stage
#pragma unroll 1
        for (int b = 0; b < 16; ++b) {
#pragma unroll
            for (int j = 0; j < 4; ++j)
                gll16(Cn + (b * 4 + j) * 256 + l * 4, stg + j * 256);
            WAITVM(0);
#pragma unroll
            for (int j = 0; j < 4; ++j) {
                const int s = b * 8 + j * 2 + half;
                const f4v c4 = *(const f4v*)(stg + j * 256 + l * 4);
                const float wsc = sSc[wv][s] * iL;
                f4v o = c4 * (1.0f - wsc * e4) + wsc * v4;
                __builtin_nontemporal_store(o, (f4v*)(Co + (size_t)s * Ff + f4));
            }
        }
    }
}

// ---------------------------------------------------------------------------
extern "C" void kernel_launch(void* const* d_in, const int* in_sizes, int n_in,
                              void* d_out, int out_size, void* d_ws, size_t ws_size,
                              hipStream_t stream)
{
    const float* h_prev = (const float*)d_in[0];
    const float* C      = (const float*)d_in[1];
    const float* Wk     = (const float*)d_in[2];
    const float* bk     = (const float*)d_in[3];
    const float* Wb     = (const float*)d_in[4];
    const float* bb     = (const float*)d_in[5];
    const float* We     = (const float*)d_in[6];
    const float* be     = (const float*)d_in[7];
    const float* Wv     = (const float*)d_in[8];
    const float* bv     = (const float*)d_in[9];
    const float* Wih    = (const float*)d_in[10];
    const float* Whh    = (const float*)d_in[11];
    const float* bih    = (const float*)d_in[12];
    const float* bhh    = (const float*)d_in[13];

    float* out  = (float*)d_out;
    float* ho   = out + HO_OFF;
    float* Cnew = out + C_OFF;
    float* kbuf = out + K_OFF;
    float* rbuf = out + R_OFF;

    short* wsB = (short*)d_ws;

    prep_weights<<<W_TOT / 256, 256, 0, stream>>>(Wk, Whh, Wih, We, Wv, wsB);

    mega_kernel<<<Nn / 8, 512, 0, stream>>>(
        C, h_prev, wsB, Wb, bb, bk, bhh, bih, be, bv,
        ho, Cnew, kbuf, rbuf);
}